// Round 1
// baseline (771.937 us; speedup 1.0000x reference)
//
#include <hip/hip_runtime.h>
#include <hip/hip_bf16.h>
#include <stdint.h>

// Problem constants
#define T_TOK 4096
#define HDIM  2048
#define IDIM  1408
#define NEXP  8
#define TOPK  2
#define NROWS (T_TOK*TOPK)   // 8192 grouped rows
#define ROWPAD 128
#define MAX_TILES 72
#define BK 32

typedef __attribute__((ext_vector_type(8))) short short8;   // 8 bf16 (4 VGPRs)
typedef __attribute__((ext_vector_type(4))) float f32x4;
using bf16 = __hip_bfloat16;

// ---------------- async global->LDS (16B per lane) ----------------
__device__ __forceinline__ void gload16(const void* g, void* l) {
    __builtin_amdgcn_global_load_lds(
        (const __attribute__((address_space(1))) uint32_t*)g,
        (__attribute__((address_space(3))) uint32_t*)l,
        16, 0, 0);
}

// ---------------- small bookkeeping kernels ----------------
// meta layout (ints): [0..7] counts, [8..15] cursor, [16..23] offsets,
//                     [24] n_tiles, [32 + 4*t ...] tile desc {row_start, rows, expert, pad}
__global__ void hist_k(const int* __restrict__ sel, int* __restrict__ meta) {
    int i = blockIdx.x*256 + threadIdx.x;
    if (i >= NROWS) return;
    int t = i & (T_TOK-1), k = i >> 12;
    atomicAdd(&meta[sel[t*TOPK + k]], 1);
}

__global__ void desc_k(int* __restrict__ meta) {
    if (threadIdx.x != 0) return;
    int off = 0, nt = 0;
    for (int e = 0; e < NEXP; e++) {
        int c = meta[e];
        meta[16+e] = off;
        meta[8+e]  = off;           // cursor for scatter
        for (int s = 0; s < c; s += 128) {
            meta[32 + nt*4 + 0] = off + s;
            meta[32 + nt*4 + 1] = (c - s) < 128 ? (c - s) : 128;
            meta[32 + nt*4 + 2] = e;
            nt++;
        }
        off += c;
    }
    meta[24] = nt;
}

__global__ void scatter_k(const int* __restrict__ sel, const float* __restrict__ rw,
                          int* __restrict__ meta, int* __restrict__ token,
                          float* __restrict__ prob) {
    int i = blockIdx.x*256 + threadIdx.x;
    if (i >= NROWS) return;
    int t = i & (T_TOK-1), k = i >> 12;
    int e = sel[t*TOPK + k];
    int r = atomicAdd(&meta[8+e], 1);
    token[r] = t;
    prob[r]  = rw[t*TOPK + k];
}

// gather hidden_states rows into grouped bf16 matrix Xg [NROWS+pad][HDIM]
__global__ void gather_k(const float* __restrict__ hid, const int* __restrict__ token,
                         bf16* __restrict__ Xg) {
    int i = blockIdx.x*256 + threadIdx.x;        // one thread = 4 elems
    int r  = i >> 9;                              // / (HDIM/4=512)
    int c4 = i & 511;
    int t = token[r];
    float4 v = *((const float4*)(hid + (size_t)t*HDIM) + c4);
    union { bf16 h[4]; uint2 u; } o;
    o.h[0] = __float2bfloat16(v.x); o.h[1] = __float2bfloat16(v.y);
    o.h[2] = __float2bfloat16(v.z); o.h[3] = __float2bfloat16(v.w);
    *(uint2*)(Xg + (size_t)r*HDIM + c4*4) = o.u;
}

// transpose + convert: in [E][Kd][Nd] f32  ->  out [E][Nd][Kd] bf16
__global__ void tcvt_k(const float* __restrict__ in, bf16* __restrict__ outp,
                       int Kd, int Nd) {
    __shared__ float tile[32][33];
    int e = blockIdx.z;
    const float* src = in + (size_t)e*Kd*Nd;
    bf16* dst = outp + (size_t)e*Kd*Nd;
    int n0 = blockIdx.x*32, k0 = blockIdx.y*32;
    int tx = threadIdx.x & 31, ty = threadIdx.x >> 5;   // ty 0..7
    #pragma unroll
    for (int i = 0; i < 4; i++)
        tile[ty + i*8][tx] = src[(size_t)(k0 + ty + i*8)*Nd + n0 + tx];
    __syncthreads();
    #pragma unroll
    for (int i = 0; i < 4; i++)
        dst[(size_t)(n0 + ty + i*8)*Kd + k0 + tx] = __float2bfloat16(tile[tx][ty + i*8]);
}

// ---------------- grouped GEMM 1: fused gate+up, silu*up*prob -> h (bf16) ----------------
// A = Xg [rows][HDIM] (grouped, ragged), B = Wg_t/Wu_t [E][IDIM][HDIM] (n-major)
__global__ __launch_bounds__(256, 2) void gemm_gateup(
    const bf16* __restrict__ Xg, const bf16* __restrict__ Wg,
    const bf16* __restrict__ Wu, const int* __restrict__ meta,
    const float* __restrict__ prob, bf16* __restrict__ Hout)
{
    __shared__ __align__(16) bf16 As [2][128*BK];
    __shared__ __align__(16) bf16 Bgs[2][128*BK];
    __shared__ __align__(16) bf16 Bus[2][128*BK];

    int tile = blockIdx.y;
    if (tile >= meta[24]) return;
    int row_start = meta[32 + tile*4 + 0];
    int rows      = meta[32 + tile*4 + 1];
    int e         = meta[32 + tile*4 + 2];
    int ntile     = blockIdx.x;

    int tid = threadIdx.x;
    int w = tid >> 6, l = tid & 63;
    int wr = w >> 1, wc = w & 1;

    const bf16* Abase  = Xg + (size_t)row_start * HDIM;
    const bf16* Bgbase = Wg + ((size_t)e * IDIM + (size_t)ntile*128) * HDIM;
    const bf16* Bubase = Wu + ((size_t)e * IDIM + (size_t)ntile*128) * HDIM;

    int si  = w*2;                       // this wave's 2 chunk slots
    int sr0 = (si+0)*16 + (l >> 2);      // row covered by chunk 0
    int sr1 = (si+1)*16 + (l >> 2);
    int sk  = (l & 3) * 8;               // k start within BK

    f32x4 accg[4][4], accu[4][4];
    #pragma unroll
    for (int i = 0; i < 4; i++)
        #pragma unroll
        for (int j = 0; j < 4; j++) {
            accg[i][j] = f32x4{0.f,0.f,0.f,0.f};
            accu[i][j] = f32x4{0.f,0.f,0.f,0.f};
        }

    auto stage = [&](int buf, int step) {
        size_t kb = (size_t)step*BK + sk;
        gload16(Abase  + (size_t)sr0*HDIM + kb, &As [buf][(si+0)*512]);
        gload16(Abase  + (size_t)sr1*HDIM + kb, &As [buf][(si+1)*512]);
        gload16(Bgbase + (size_t)sr0*HDIM + kb, &Bgs[buf][(si+0)*512]);
        gload16(Bgbase + (size_t)sr1*HDIM + kb, &Bgs[buf][(si+1)*512]);
        gload16(Bubase + (size_t)sr0*HDIM + kb, &Bus[buf][(si+0)*512]);
        gload16(Bubase + (size_t)sr1*HDIM + kb, &Bus[buf][(si+1)*512]);
    };

    int fr = l & 15, fg = l >> 4;
    const int NSTEP = HDIM / BK;   // 64

    stage(0, 0);
    __syncthreads();
    int buf = 0;
    for (int step = 0; step < NSTEP; ++step) {
        if (step + 1 < NSTEP) stage(buf ^ 1, step + 1);
        short8 a[4], bg[4], bu[4];
        #pragma unroll
        for (int mi = 0; mi < 4; mi++)
            a[mi] = *(const short8*)&As[buf][(wr*64 + mi*16 + fr)*BK + fg*8];
        #pragma unroll
        for (int ni = 0; ni < 4; ni++) {
            bg[ni] = *(const short8*)&Bgs[buf][(wc*64 + ni*16 + fr)*BK + fg*8];
            bu[ni] = *(const short8*)&Bus[buf][(wc*64 + ni*16 + fr)*BK + fg*8];
        }
        #pragma unroll
        for (int mi = 0; mi < 4; mi++)
            #pragma unroll
            for (int ni = 0; ni < 4; ni++) {
                accg[mi][ni] = __builtin_amdgcn_mfma_f32_16x16x32_bf16(a[mi], bg[ni], accg[mi][ni], 0, 0, 0);
                accu[mi][ni] = __builtin_amdgcn_mfma_f32_16x16x32_bf16(a[mi], bu[ni], accu[mi][ni], 0, 0, 0);
            }
        __syncthreads();
        buf ^= 1;
    }

    // epilogue: h = silu(g) * u * prob  (prob folded here; down() is linear)
    #pragma unroll
    for (int mi = 0; mi < 4; mi++) {
        #pragma unroll
        for (int ni = 0; ni < 4; ni++) {
            f32x4 g = accg[mi][ni], u = accu[mi][ni];
            #pragma unroll
            for (int j = 0; j < 4; j++) {
                int rl = wr*64 + mi*16 + fg*4 + j;
                if (rl < rows) {
                    int rgl = row_start + rl;
                    float gv = g[j];
                    float hv = (gv / (1.f + __expf(-gv))) * u[j] * prob[rgl];
                    int col = ntile*128 + wc*64 + ni*16 + fr;
                    Hout[(size_t)rgl*IDIM + col] = __float2bfloat16(hv);
                }
            }
        }
    }
}

// ---------------- grouped GEMM 2: down proj, atomic scatter-add to out ----------------
// A = h [rows][IDIM], B = Wd_t [E][HDIM][IDIM] (n-major)
__global__ __launch_bounds__(256, 2) void gemm_down(
    const bf16* __restrict__ Hin, const bf16* __restrict__ Wd,
    const int* __restrict__ meta, const int* __restrict__ token,
    float* __restrict__ outp)
{
    __shared__ __align__(16) bf16 As[2][128*BK];
    __shared__ __align__(16) bf16 Bs[2][128*BK];

    int tile = blockIdx.y;
    if (tile >= meta[24]) return;
    int row_start = meta[32 + tile*4 + 0];
    int rows      = meta[32 + tile*4 + 1];
    int e         = meta[32 + tile*4 + 2];
    int ntile     = blockIdx.x;

    int tid = threadIdx.x;
    int w = tid >> 6, l = tid & 63;
    int wr = w >> 1, wc = w & 1;

    const bf16* Abase = Hin + (size_t)row_start * IDIM;
    const bf16* Bbase = Wd + ((size_t)e * HDIM + (size_t)ntile*128) * IDIM;

    int si  = w*2;
    int sr0 = (si+0)*16 + (l >> 2);
    int sr1 = (si+1)*16 + (l >> 2);
    int sk  = (l & 3) * 8;

    f32x4 acc[4][4];
    #pragma unroll
    for (int i = 0; i < 4; i++)
        #pragma unroll
        for (int j = 0; j < 4; j++) acc[i][j] = f32x4{0.f,0.f,0.f,0.f};

    auto stage = [&](int buf, int step) {
        size_t kb = (size_t)step*BK + sk;
        gload16(Abase + (size_t)sr0*IDIM + kb, &As[buf][(si+0)*512]);
        gload16(Abase + (size_t)sr1*IDIM + kb, &As[buf][(si+1)*512]);
        gload16(Bbase + (size_t)sr0*IDIM + kb, &Bs[buf][(si+0)*512]);
        gload16(Bbase + (size_t)sr1*IDIM + kb, &Bs[buf][(si+1)*512]);
    };

    int fr = l & 15, fg = l >> 4;
    const int NSTEP = IDIM / BK;   // 44

    stage(0, 0);
    __syncthreads();
    int buf = 0;
    for (int step = 0; step < NSTEP; ++step) {
        if (step + 1 < NSTEP) stage(buf ^ 1, step + 1);
        short8 a[4], b[4];
        #pragma unroll
        for (int mi = 0; mi < 4; mi++)
            a[mi] = *(const short8*)&As[buf][(wr*64 + mi*16 + fr)*BK + fg*8];
        #pragma unroll
        for (int ni = 0; ni < 4; ni++)
            b[ni] = *(const short8*)&Bs[buf][(wc*64 + ni*16 + fr)*BK + fg*8];
        #pragma unroll
        for (int mi = 0; mi < 4; mi++)
            #pragma unroll
            for (int ni = 0; ni < 4; ni++)
                acc[mi][ni] = __builtin_amdgcn_mfma_f32_16x16x32_bf16(a[mi], b[ni], acc[mi][ni], 0, 0, 0);
        __syncthreads();
        buf ^= 1;
    }

    #pragma unroll
    for (int mi = 0; mi < 4; mi++) {
        #pragma unroll
        for (int ni = 0; ni < 4; ni++) {
            #pragma unroll
            for (int j = 0; j < 4; j++) {
                int rl = wr*64 + mi*16 + fg*4 + j;
                if (rl < rows) {
                    int r = row_start + rl;
                    int col = ntile*128 + wc*64 + ni*16 + fr;
                    atomicAdd(&outp[(size_t)token[r]*HDIM + col], acc[mi][ni][j]);
                }
            }
        }
    }
}

// ---------------- host launch ----------------
extern "C" void kernel_launch(void* const* d_in, const int* in_sizes, int n_in,
                              void* d_out, int out_size, void* d_ws, size_t ws_size,
                              hipStream_t stream) {
    const float* hid = (const float*)d_in[0];
    const float* rw  = (const float*)d_in[1];
    const int*   sel = (const int*)  d_in[2];
    const float* gw  = (const float*)d_in[3];
    const float* uw  = (const float*)d_in[4];
    const float* dw  = (const float*)d_in[5];
    float* outp = (float*)d_out;

    // ws layout
    uint8_t* ws = (uint8_t*)d_ws;
    size_t off = 0;
    auto alloc = [&](size_t bytes) { size_t o = off; off = (off + bytes + 255) & ~(size_t)255; return o; };
    size_t o_meta  = alloc(4096);
    size_t o_token = alloc(NROWS * sizeof(int));
    size_t o_prob  = alloc(NROWS * sizeof(float));
    size_t o_xg    = alloc((size_t)(NROWS + ROWPAD) * HDIM * sizeof(bf16));
    size_t o_wg    = alloc((size_t)NEXP * IDIM * HDIM * sizeof(bf16));
    size_t o_wu    = alloc((size_t)NEXP * IDIM * HDIM * sizeof(bf16));
    size_t o_wd    = alloc((size_t)NEXP * HDIM * IDIM * sizeof(bf16));
    size_t o_h     = alloc((size_t)(NROWS + ROWPAD) * IDIM * sizeof(bf16));
    if (ws_size < off) {    // can't run: make failure unambiguous (out = 0)
        hipMemsetAsync(d_out, 0, (size_t)out_size * sizeof(float), stream);
        return;
    }

    int*   meta  = (int*)  (ws + o_meta);
    int*   token = (int*)  (ws + o_token);
    float* prob  = (float*)(ws + o_prob);
    bf16*  Xg    = (bf16*) (ws + o_xg);
    bf16*  Wgt   = (bf16*) (ws + o_wg);
    bf16*  Wut   = (bf16*) (ws + o_wu);
    bf16*  Wdt   = (bf16*) (ws + o_wd);
    bf16*  Hb    = (bf16*) (ws + o_h);

    hipMemsetAsync(meta, 0, 64, stream);                                   // counts+cursor
    hipMemsetAsync(d_out, 0, (size_t)out_size * sizeof(float), stream);    // atomic target

    hist_k   <<<NROWS/256, 256, 0, stream>>>(sel, meta);
    desc_k   <<<1, 64, 0, stream>>>(meta);
    scatter_k<<<NROWS/256, 256, 0, stream>>>(sel, rw, meta, token, prob);
    gather_k <<<(NROWS*(HDIM/4))/256, 256, 0, stream>>>(hid, token, Xg);

    // weights: [E][K][N] f32 -> [E][N][K] bf16
    tcvt_k<<<dim3(IDIM/32, HDIM/32, NEXP), 256, 0, stream>>>(gw, Wgt, HDIM, IDIM);
    tcvt_k<<<dim3(IDIM/32, HDIM/32, NEXP), 256, 0, stream>>>(uw, Wut, HDIM, IDIM);
    tcvt_k<<<dim3(HDIM/32, IDIM/32, NEXP), 256, 0, stream>>>(dw, Wdt, IDIM, HDIM);

    gemm_gateup<<<dim3(IDIM/128, MAX_TILES), 256, 0, stream>>>(Xg, Wgt, Wut, meta, prob, Hb);
    gemm_down  <<<dim3(HDIM/128, MAX_TILES), 256, 0, stream>>>(Hb, Wdt, meta, token, outp);
}

// Round 4
// 730.936 us; speedup vs baseline: 1.0561x; 1.0561x over previous
//
#include <hip/hip_runtime.h>
#include <hip/hip_bf16.h>
#include <stdint.h>

// Problem constants
#define T_TOK 4096
#define HDIM  2048
#define IDIM  1408
#define NEXP  8
#define TOPK  2
#define NROWS (T_TOK*TOPK)   // 8192 grouped rows
#define ROWPAD 128
#define MAX_TILES 72
#define BK 32

typedef __attribute__((ext_vector_type(8))) short short8;   // 8 bf16 (4 VGPRs)
typedef __attribute__((ext_vector_type(4))) float f32x4;
using bf16 = __hip_bfloat16;

// ---------------- async global->LDS (16B per lane) ----------------
__device__ __forceinline__ void gload16(const void* g, void* l) {
    __builtin_amdgcn_global_load_lds(
        (const __attribute__((address_space(1))) uint32_t*)g,
        (__attribute__((address_space(3))) uint32_t*)l,
        16, 0, 0);
}

// LDS chunk swizzle: within a row of BK=32 bf16 (4 chunks of 8 bf16=16B),
// data chunk c is stored at position c ^ s(row), s(row) = (row ^ (row>>2)) & 3.
// Read groups of 16 lanes then spread across 8 banks at 2-way (free, m136).
// global_load_lds writes linearly, so we permute the GLOBAL source chunk per
// lane (rule #21: linear dest + inverse-swizzled source + swizzled read).

// ---------------- small bookkeeping kernels ----------------
// meta layout (ints): [0..7] counts, [8..15] cursor, [16..23] offsets,
//                     [24] n_tiles, [32 + 4*t ...] tile desc {row_start, rows, expert, pad}
__global__ void hist_k(const int* __restrict__ sel, int* __restrict__ meta) {
    int i = blockIdx.x*256 + threadIdx.x;
    if (i >= NROWS) return;
    int t = i & (T_TOK-1), k = i >> 12;
    atomicAdd(&meta[sel[t*TOPK + k]], 1);
}

__global__ void desc_k(int* __restrict__ meta) {
    if (threadIdx.x != 0) return;
    int off = 0, nt = 0;
    for (int e = 0; e < NEXP; e++) {
        int c = meta[e];
        meta[16+e] = off;
        meta[8+e]  = off;           // cursor for scatter
        for (int s = 0; s < c; s += 128) {
            meta[32 + nt*4 + 0] = off + s;
            meta[32 + nt*4 + 1] = (c - s) < 128 ? (c - s) : 128;
            meta[32 + nt*4 + 2] = e;
            nt++;
        }
        off += c;
    }
    meta[24] = nt;
}

__global__ void scatter_k(const int* __restrict__ sel, const float* __restrict__ rw,
                          int* __restrict__ meta, int* __restrict__ token,
                          float* __restrict__ prob) {
    int i = blockIdx.x*256 + threadIdx.x;
    if (i >= NROWS) return;
    int t = i & (T_TOK-1), k = i >> 12;
    int e = sel[t*TOPK + k];
    int r = atomicAdd(&meta[8+e], 1);
    token[r] = t;
    prob[r]  = rw[t*TOPK + k];
}

// gather hidden_states rows into grouped bf16 matrix Xg [NROWS+pad][HDIM]
__global__ void gather_k(const float* __restrict__ hid, const int* __restrict__ token,
                         bf16* __restrict__ Xg) {
    int i = blockIdx.x*256 + threadIdx.x;        // one thread = 4 elems
    int r  = i >> 9;                              // / (HDIM/4=512)
    int c4 = i & 511;
    int t = token[r];
    float4 v = *((const float4*)(hid + (size_t)t*HDIM) + c4);
    union { bf16 h[4]; uint2 u; } o;
    o.h[0] = __float2bfloat16(v.x); o.h[1] = __float2bfloat16(v.y);
    o.h[2] = __float2bfloat16(v.z); o.h[3] = __float2bfloat16(v.w);
    *(uint2*)(Xg + (size_t)r*HDIM + c4*4) = o.u;
}

// transpose + convert: in [E][Kd][Nd] f32  ->  out [E][Nd][Kd] bf16
__global__ void tcvt_k(const float* __restrict__ in, bf16* __restrict__ outp,
                       int Kd, int Nd) {
    __shared__ float tile[32][33];
    int e = blockIdx.z;
    const float* src = in + (size_t)e*Kd*Nd;
    bf16* dst = outp + (size_t)e*Kd*Nd;
    int n0 = blockIdx.x*32, k0 = blockIdx.y*32;
    int tx = threadIdx.x & 31, ty = threadIdx.x >> 5;   // ty 0..7
    #pragma unroll
    for (int i = 0; i < 4; i++)
        tile[ty + i*8][tx] = src[(size_t)(k0 + ty + i*8)*Nd + n0 + tx];
    __syncthreads();
    #pragma unroll
    for (int i = 0; i < 4; i++)
        dst[(size_t)(n0 + ty + i*8)*Kd + k0 + tx] = __float2bfloat16(tile[tx][ty + i*8]);
}

// ---------------- grouped GEMM 1: fused gate+up, silu*up*prob -> h (bf16) ----------------
// A = Xg [rows][HDIM] (grouped, ragged), B = Wg_t/Wu_t [E][IDIM][HDIM] (n-major)
// 1D grid, XCD-chunked: each XCD gets 9 row-tiles x all ntiles (A L2-resident).
__global__ __launch_bounds__(256, 2) void gemm_gateup(
    const bf16* __restrict__ Xg, const bf16* __restrict__ Wg,
    const bf16* __restrict__ Wu, const int* __restrict__ meta,
    const float* __restrict__ prob, bf16* __restrict__ Hout)
{
    __shared__ __align__(16) bf16 As [2][128*BK];
    __shared__ __align__(16) bf16 Bgs[2][128*BK];
    __shared__ __align__(16) bf16 Bus[2][128*BK];

    const int NTN = IDIM/128;            // 11
    int cpx = gridDim.x >> 3;            // blocks per XCD chunk
    int bid = blockIdx.x;
    int swz = (bid & 7) * cpx + (bid >> 3);   // logical work id, ntile-fastest
    int ntile = swz % NTN;
    int tile  = swz / NTN;

    if (tile >= meta[24]) return;
    int row_start = meta[32 + tile*4 + 0];
    int rows      = meta[32 + tile*4 + 1];
    int e         = meta[32 + tile*4 + 2];

    int tid = threadIdx.x;
    int w = tid >> 6, l = tid & 63;
    int wr = w >> 1, wc = w & 1;

    const bf16* Abase  = Xg + (size_t)row_start * HDIM;
    const bf16* Bgbase = Wg + ((size_t)e * IDIM + (size_t)ntile*128) * HDIM;
    const bf16* Bubase = Wu + ((size_t)e * IDIM + (size_t)ntile*128) * HDIM;

    int si  = w*2;                       // this wave's 2 chunk slots
    int sr0 = (si+0)*16 + (l >> 2);      // row covered by chunk 0
    int sr1 = (si+1)*16 + (l >> 2);
    // swizzled source chunk: s(row) = ((l>>2) ^ (l>>4)) & 3  (same for sr0/sr1)
    int kc  = (((l & 3) ^ ((l >> 2) ^ (l >> 4))) & 3) * 8;

    f32x4 accg[4][4], accu[4][4];
    #pragma unroll
    for (int i = 0; i < 4; i++)
        #pragma unroll
        for (int j = 0; j < 4; j++) {
            accg[i][j] = f32x4{0.f,0.f,0.f,0.f};
            accu[i][j] = f32x4{0.f,0.f,0.f,0.f};
        }

    auto stage = [&](int buf, int step) {
        size_t kb = (size_t)step*BK + kc;
        gload16(Abase  + (size_t)sr0*HDIM + kb, &As [buf][(si+0)*512]);
        gload16(Abase  + (size_t)sr1*HDIM + kb, &As [buf][(si+1)*512]);
        gload16(Bgbase + (size_t)sr0*HDIM + kb, &Bgs[buf][(si+0)*512]);
        gload16(Bgbase + (size_t)sr1*HDIM + kb, &Bgs[buf][(si+1)*512]);
        gload16(Bubase + (size_t)sr0*HDIM + kb, &Bus[buf][(si+0)*512]);
        gload16(Bubase + (size_t)sr1*HDIM + kb, &Bus[buf][(si+1)*512]);
    };

    int fr = l & 15, fg = l >> 4;
    int sxor = ((fr ^ (fr >> 2)) & 3) * 8;   // read-side swizzle, indep of mi/wr
    int fg8s = (fg * 8) ^ sxor;              // swizzled chunk byte offset (bf16 units)
    const int NSTEP = HDIM / BK;   // 64

    stage(0, 0);
    __syncthreads();
    int buf = 0;
    for (int step = 0; step < NSTEP; ++step) {
        if (step + 1 < NSTEP) stage(buf ^ 1, step + 1);
        short8 a[4], bg[4], bu[4];
        #pragma unroll
        for (int mi = 0; mi < 4; mi++)
            a[mi] = *(const short8*)&As[buf][(wr*64 + mi*16 + fr)*BK + fg8s];
        #pragma unroll
        for (int ni = 0; ni < 4; ni++) {
            bg[ni] = *(const short8*)&Bgs[buf][(wc*64 + ni*16 + fr)*BK + fg8s];
            bu[ni] = *(const short8*)&Bus[buf][(wc*64 + ni*16 + fr)*BK + fg8s];
        }
        #pragma unroll
        for (int mi = 0; mi < 4; mi++)
            #pragma unroll
            for (int ni = 0; ni < 4; ni++) {
                accg[mi][ni] = __builtin_amdgcn_mfma_f32_16x16x32_bf16(a[mi], bg[ni], accg[mi][ni], 0, 0, 0);
                accu[mi][ni] = __builtin_amdgcn_mfma_f32_16x16x32_bf16(a[mi], bu[ni], accu[mi][ni], 0, 0, 0);
            }
        __syncthreads();
        buf ^= 1;
    }

    // epilogue: h = silu(g) * u * prob  (prob folded here; down() is linear)
    #pragma unroll
    for (int mi = 0; mi < 4; mi++) {
        #pragma unroll
        for (int ni = 0; ni < 4; ni++) {
            f32x4 g = accg[mi][ni], u = accu[mi][ni];
            #pragma unroll
            for (int j = 0; j < 4; j++) {
                int rl = wr*64 + mi*16 + fg*4 + j;
                if (rl < rows) {
                    int rgl = row_start + rl;
                    float gv = g[j];
                    float hv = (gv / (1.f + __expf(-gv))) * u[j] * prob[rgl];
                    int col = ntile*128 + wc*64 + ni*16 + fr;
                    Hout[(size_t)rgl*IDIM + col] = __float2bfloat16(hv);
                }
            }
        }
    }
}

// ---------------- grouped GEMM 2: down proj, atomic scatter-add to out ----------------
// A = h [rows][IDIM], B = Wd_t [E][HDIM][IDIM] (n-major)
__global__ __launch_bounds__(256, 2) void gemm_down(
    const bf16* __restrict__ Hin, const bf16* __restrict__ Wd,
    const int* __restrict__ meta, const int* __restrict__ token,
    float* __restrict__ outp)
{
    __shared__ __align__(16) bf16 As[2][128*BK];
    __shared__ __align__(16) bf16 Bs[2][128*BK];

    const int NTN = HDIM/128;            // 16
    int cpx = gridDim.x >> 3;
    int bid = blockIdx.x;
    int swz = (bid & 7) * cpx + (bid >> 3);
    int ntile = swz % NTN;
    int tile  = swz / NTN;

    if (tile >= meta[24]) return;
    int row_start = meta[32 + tile*4 + 0];
    int rows      = meta[32 + tile*4 + 1];
    int e         = meta[32 + tile*4 + 2];

    int tid = threadIdx.x;
    int w = tid >> 6, l = tid & 63;
    int wr = w >> 1, wc = w & 1;

    const bf16* Abase = Hin + (size_t)row_start * IDIM;
    const bf16* Bbase = Wd + ((size_t)e * HDIM + (size_t)ntile*128) * IDIM;

    int si  = w*2;
    int sr0 = (si+0)*16 + (l >> 2);
    int sr1 = (si+1)*16 + (l >> 2);
    int kc  = (((l & 3) ^ ((l >> 2) ^ (l >> 4))) & 3) * 8;

    f32x4 acc[4][4];
    #pragma unroll
    for (int i = 0; i < 4; i++)
        #pragma unroll
        for (int j = 0; j < 4; j++) acc[i][j] = f32x4{0.f,0.f,0.f,0.f};

    auto stage = [&](int buf, int step) {
        size_t kb = (size_t)step*BK + kc;
        gload16(Abase + (size_t)sr0*IDIM + kb, &As[buf][(si+0)*512]);
        gload16(Abase + (size_t)sr1*IDIM + kb, &As[buf][(si+1)*512]);
        gload16(Bbase + (size_t)sr0*IDIM + kb, &Bs[buf][(si+0)*512]);
        gload16(Bbase + (size_t)sr1*IDIM + kb, &Bs[buf][(si+1)*512]);
    };

    int fr = l & 15, fg = l >> 4;
    int sxor = ((fr ^ (fr >> 2)) & 3) * 8;
    int fg8s = (fg * 8) ^ sxor;
    const int NSTEP = IDIM / BK;   // 44

    stage(0, 0);
    __syncthreads();
    int buf = 0;
    for (int step = 0; step < NSTEP; ++step) {
        if (step + 1 < NSTEP) stage(buf ^ 1, step + 1);
        short8 a[4], b[4];
        #pragma unroll
        for (int mi = 0; mi < 4; mi++)
            a[mi] = *(const short8*)&As[buf][(wr*64 + mi*16 + fr)*BK + fg8s];
        #pragma unroll
        for (int ni = 0; ni < 4; ni++)
            b[ni] = *(const short8*)&Bs[buf][(wc*64 + ni*16 + fr)*BK + fg8s];
        #pragma unroll
        for (int mi = 0; mi < 4; mi++)
            #pragma unroll
            for (int ni = 0; ni < 4; ni++)
                acc[mi][ni] = __builtin_amdgcn_mfma_f32_16x16x32_bf16(a[mi], b[ni], acc[mi][ni], 0, 0, 0);
        __syncthreads();
        buf ^= 1;
    }

    #pragma unroll
    for (int mi = 0; mi < 4; mi++) {
        #pragma unroll
        for (int ni = 0; ni < 4; ni++) {
            #pragma unroll
            for (int j = 0; j < 4; j++) {
                int rl = wr*64 + mi*16 + fg*4 + j;
                if (rl < rows) {
                    int r = row_start + rl;
                    int col = ntile*128 + wc*64 + ni*16 + fr;
                    atomicAdd(&outp[(size_t)token[r]*HDIM + col], acc[mi][ni][j]);
                }
            }
        }
    }
}

// ---------------- host launch ----------------
extern "C" void kernel_launch(void* const* d_in, const int* in_sizes, int n_in,
                              void* d_out, int out_size, void* d_ws, size_t ws_size,
                              hipStream_t stream) {
    const float* hid = (const float*)d_in[0];
    const float* rw  = (const float*)d_in[1];
    const int*   sel = (const int*)  d_in[2];
    const float* gw  = (const float*)d_in[3];
    const float* uw  = (const float*)d_in[4];
    const float* dw  = (const float*)d_in[5];
    float* outp = (float*)d_out;

    // ws layout
    uint8_t* ws = (uint8_t*)d_ws;
    size_t off = 0;
    auto alloc = [&](size_t bytes) { size_t o = off; off = (off + bytes + 255) & ~(size_t)255; return o; };
    size_t o_meta  = alloc(4096);
    size_t o_token = alloc(NROWS * sizeof(int));
    size_t o_prob  = alloc(NROWS * sizeof(float));
    size_t o_xg    = alloc((size_t)(NROWS + ROWPAD) * HDIM * sizeof(bf16));
    size_t o_wg    = alloc((size_t)NEXP * IDIM * HDIM * sizeof(bf16));
    size_t o_wu    = alloc((size_t)NEXP * IDIM * HDIM * sizeof(bf16));
    size_t o_wd    = alloc((size_t)NEXP * HDIM * IDIM * sizeof(bf16));
    size_t o_h     = alloc((size_t)(NROWS + ROWPAD) * IDIM * sizeof(bf16));
    if (ws_size < off) {    // can't run: make failure unambiguous (out = 0)
        hipMemsetAsync(d_out, 0, (size_t)out_size * sizeof(float), stream);
        return;
    }

    int*   meta  = (int*)  (ws + o_meta);
    int*   token = (int*)  (ws + o_token);
    float* prob  = (float*)(ws + o_prob);
    bf16*  Xg    = (bf16*) (ws + o_xg);
    bf16*  Wgt   = (bf16*) (ws + o_wg);
    bf16*  Wut   = (bf16*) (ws + o_wu);
    bf16*  Wdt   = (bf16*) (ws + o_wd);
    bf16*  Hb    = (bf16*) (ws + o_h);

    hipMemsetAsync(meta, 0, 64, stream);                                   // counts+cursor
    hipMemsetAsync(d_out, 0, (size_t)out_size * sizeof(float), stream);    // atomic target

    hist_k   <<<NROWS/256, 256, 0, stream>>>(sel, meta);
    desc_k   <<<1, 64, 0, stream>>>(meta);
    scatter_k<<<NROWS/256, 256, 0, stream>>>(sel, rw, meta, token, prob);
    gather_k <<<(NROWS*(HDIM/4))/256, 256, 0, stream>>>(hid, token, Xg);

    // weights: [E][K][N] f32 -> [E][N][K] bf16
    tcvt_k<<<dim3(IDIM/32, HDIM/32, NEXP), 256, 0, stream>>>(gw, Wgt, HDIM, IDIM);
    tcvt_k<<<dim3(IDIM/32, HDIM/32, NEXP), 256, 0, stream>>>(uw, Wut, HDIM, IDIM);
    tcvt_k<<<dim3(HDIM/32, IDIM/32, NEXP), 256, 0, stream>>>(dw, Wdt, IDIM, HDIM);

    // 1D grids, divisible by 8 for the XCD chunk swizzle
    gemm_gateup<<<(IDIM/128)*MAX_TILES, 256, 0, stream>>>(Xg, Wgt, Wut, meta, prob, Hb);
    gemm_down  <<<(HDIM/128)*MAX_TILES, 256, 0, stream>>>(Hb, Wdt, meta, token, outp);
}